// Round 15
// baseline (243.104 us; speedup 1.0000x reference)
//
#include <hip/hip_runtime.h>

// Radius search (L2^2), single segment, M=4096 queries x N=8192 points.
// Out (float32, concat): [0,MN) packed idx (pad -1) | [MN,MN+M+1) row splits |
//                        [MN+M+1, 2MN+M+1) packed d2 (pad 0).
// Exact numpy fp32 op order (NO fma):
//   q2=(qx*qx+qy*qy)+qz*qz ; p2=(px*px+py*py)+pz*pz ; qp=(qx*px+qy*py)+qz*pz
//   d2=max((q2+p2)-2*qp, 0) ; mask: d2<=r*r  (max irrelevant for mask, r2>0)
//
// LESSONS: hipMemsetAsync in-graph costs ~40-155us regardless of size (R9/R14)
// -> never use it. Fill splits across serial kernels are invariant (R11/R13).
// R12 (58.9us) = woven count+fill K1 + scan+pack K2.
// R15 = ONE kernel: R12's woven loop, then ticket -> last-block scan ->
// device-scope flag -> all blocks spin (all 1024 co-resident via
// __launch_bounds__(256,4)) -> each wave packs its own query. K2 eliminated.
// Flags zeroed by a micro-kernel (NOT memset). Fallback: R12 path verbatim.

typedef float f32x4 __attribute__((ext_vector_type(4)));

__global__ void rs_zero(int* __restrict__ flags) {
    if (threadIdx.x == 0) { flags[0] = 0; flags[1] = 0; }
}

// ---------------- primary: fully fused kernel ----------------
__global__ __launch_bounds__(256, 4) void rs_all(
    const float* __restrict__ pts, const float* __restrict__ qs,
    const float* __restrict__ rad, int* __restrict__ counts,
    unsigned long long* __restrict__ masks,
    float* __restrict__ out_idx, float* __restrict__ out_dist,
    float* __restrict__ out_splits, int* __restrict__ splits_i,
    int* __restrict__ flags, long long MN, int N, int M) {
    int t = threadIdx.x;
    int wv = t >> 6, lane = t & 63;
    int gw = blockIdx.x * 4 + wv;       // wave id == query id
    int nWaves = gridDim.x * 4;

    bool hasQ = (gw < M);
    int qc = hasQ ? gw : 0;
    float qx = qs[3 * qc], qy = qs[3 * qc + 1], qz = qs[3 * qc + 2];
    float q2 = __fadd_rn(__fadd_rn(__fmul_rn(qx, qx), __fmul_rn(qy, qy)),
                         __fmul_rn(qz, qz));
    float r = rad[qc];
    float r2 = hasQ ? __fmul_rn(r, r) : -1.0f;  // raw d2 > -1 always

    int nc = N >> 6;                      // 64-pt mask words
    int vecIters = N >> 8;                // 256 pts/iter (4 consecutive/lane)
    long long V = MN >> 2;                // MN % 4 == 0 in harness
    long long perWave = (V + nWaves - 1) / nWaves;
    int fillIters = (int)((perWave + 63) >> 6);
    long long fbase = (long long)gw * perWave;
    long long fend = fbase + perWave;
    if (fend > V) fend = V;
    f32x4* vidx = (f32x4*)out_idx;
    f32x4* vdst = (f32x4*)out_dist;
    f32x4 vm1 = {-1.0f, -1.0f, -1.0f, -1.0f};
    f32x4 vz = {0.0f, 0.0f, 0.0f, 0.0f};

    int iters = vecIters > fillIters ? vecIters : fillIters;
    int cntLane = 0;
    int shift = (lane & 15) << 2;
    int wordSel = lane >> 4;

    for (int it = 0; it < iters; ++it) {
        if (it < fillIters) {
            long long fi = fbase + (long long)it * 64 + lane;
            if (fi < fend) { vidx[fi] = vm1; vdst[fi] = vz; }
        }
        if (it < vecIters) {
            const f32x4* pv = (const f32x4*)(pts + (size_t)it * 768);
            f32x4 v0 = pv[3 * lane + 0];
            f32x4 v1 = pv[3 * lane + 1];
            f32x4 v2 = pv[3 * lane + 2];
            float px[4] = {v0.x, v0.w, v1.z, v2.y};
            float py[4] = {v0.y, v1.x, v1.w, v2.z};
            float pz[4] = {v0.z, v1.y, v2.x, v2.w};
            unsigned nib = 0;
#pragma unroll
            for (int k = 0; k < 4; ++k) {
                float p2 = __fadd_rn(
                    __fadd_rn(__fmul_rn(px[k], px[k]), __fmul_rn(py[k], py[k])),
                    __fmul_rn(pz[k], pz[k]));
                float qp = __fadd_rn(
                    __fadd_rn(__fmul_rn(qx, px[k]), __fmul_rn(qy, py[k])),
                    __fmul_rn(qz, pz[k]));
                float d2 = __fsub_rn(__fadd_rn(q2, p2), __fmul_rn(2.0f, qp));
                bool pred = (d2 <= r2);
                nib |= (pred ? 1u : 0u) << k;
                cntLane += pred ? 1 : 0;
            }
            unsigned long long contrib = (unsigned long long)nib << shift;
#pragma unroll
            for (int s = 1; s < 16; s <<= 1) contrib |= __shfl_xor(contrib, s, 64);
            if (hasQ && (lane & 15) == 0)
                masks[(long long)gw * nc + (it << 2) + wordSel] = contrib;
        }
    }
    for (int c = vecIters << 2; c < nc; ++c) {  // tail (N%256 != 0)
        int p = (c << 6) + lane;
        bool vld = (p < N);
        int pcl = vld ? p : 0;
        float px = pts[3 * pcl], py = pts[3 * pcl + 1], pz = pts[3 * pcl + 2];
        float p2 = __fadd_rn(__fadd_rn(__fmul_rn(px, px), __fmul_rn(py, py)),
                             __fmul_rn(pz, pz));
        float qp = __fadd_rn(__fadd_rn(__fmul_rn(qx, px), __fmul_rn(qy, py)),
                             __fmul_rn(qz, pz));
        float d2 = __fsub_rn(__fadd_rn(q2, p2), __fmul_rn(2.0f, qp));
        bool pred = vld && (d2 <= r2);
        unsigned long long b = __ballot(pred);
        if (hasQ && lane == 0) masks[(long long)gw * nc + c] = b;
        cntLane += pred ? 1 : 0;
    }
    for (int off = 32; off > 0; off >>= 1) cntLane += __shfl_down(cntLane, off, 64);
    if (hasQ && lane == 0) counts[gw] = cntLane;

    // ---- ticket: last block to arrive scans counts -> splits ----
    __shared__ int s_last;
    __shared__ int s_scan[256];
    __syncthreads();
    if (t == 0) {
        __threadfence();  // counts + fills device-visible before ticket
        int old = atomicAdd(&flags[0], 1);
        s_last = (old == (int)gridDim.x - 1) ? 1 : 0;
    }
    __syncthreads();
    if (s_last) {
        __threadfence();
        volatile const int* vcounts = (volatile const int*)counts;
        int c[16];
        int sum = 0;
        int b16 = t * 16;
#pragma unroll
        for (int i = 0; i < 16; ++i) {
            int idx = b16 + i;
            int v = (idx < M) ? vcounts[idx] : 0;
            c[i] = sum;
            sum += v;
        }
        s_scan[t] = sum;
        __syncthreads();
        for (int off = 1; off < 256; off <<= 1) {
            int add = (t >= off) ? s_scan[t - off] : 0;
            __syncthreads();
            s_scan[t] += add;
            __syncthreads();
        }
        int excl = (t == 0) ? 0 : s_scan[t - 1];
#pragma unroll
        for (int i = 0; i < 16; ++i) {
            int idx = b16 + i;
            if (idx < M) {
                int v = excl + c[i];
                splits_i[idx] = v;
                out_splits[idx] = (float)v;
            }
        }
        if (t == 255) {
            splits_i[M] = excl + sum;
            out_splits[M] = (float)(excl + sum);
        }
        __syncthreads();
        if (t == 0) {
            __threadfence();  // splits device-visible before flag
            atomicExch(&flags[1], 1);
        }
    }

    // ---- all blocks: spin on device-scope atomic flag (all co-resident) ----
    if (t == 0) {
        while (atomicAdd(&flags[1], 0) == 0) { __builtin_amdgcn_s_sleep(2); }
    }
    __syncthreads();
    __threadfence();

    // ---- pack own query from own masks ----
    if (!hasQ) return;
    long long base = *(volatile const int*)&splits_i[gw];
    const unsigned long long* mq = masks + (long long)gw * nc;
    unsigned long long w0 = (lane < nc) ? mq[lane] : 0ull;
    unsigned long long w1 = (lane + 64 < nc) ? mq[lane + 64] : 0ull;
    int c0 = __popcll(w0), c1 = __popcll(w1);
    int i0 = c0, i1 = c1;
    for (int off = 1; off < 64; off <<= 1) {
        int t0 = __shfl_up(i0, off, 64);
        int t1 = __shfl_up(i1, off, 64);
        if (lane >= off) { i0 += t0; i1 += t1; }
    }
    int total0 = __shfl(i0, 63, 64);

    long long o = base + (i0 - c0);
    int pbase = lane << 6;
    unsigned long long mm = w0;
    while (mm) {
        int b = __ffsll((long long)mm) - 1;
        int p = pbase + b;
        float px = pts[3 * p], py = pts[3 * p + 1], pz = pts[3 * p + 2];
        float p2 = __fadd_rn(__fadd_rn(__fmul_rn(px, px), __fmul_rn(py, py)),
                             __fmul_rn(pz, pz));
        float qp = __fadd_rn(__fadd_rn(__fmul_rn(qx, px), __fmul_rn(qy, py)),
                             __fmul_rn(qz, pz));
        float d2 = fmaxf(__fsub_rn(__fadd_rn(q2, p2), __fmul_rn(2.0f, qp)), 0.0f);
        out_idx[o] = (float)p;
        out_dist[o] = d2;
        ++o;
        mm &= mm - 1;
    }
    o = base + total0 + (i1 - c1);
    pbase = (lane + 64) << 6;
    mm = w1;
    while (mm) {
        int b = __ffsll((long long)mm) - 1;
        int p = pbase + b;
        float px = pts[3 * p], py = pts[3 * p + 1], pz = pts[3 * p + 2];
        float p2 = __fadd_rn(__fadd_rn(__fmul_rn(px, px), __fmul_rn(py, py)),
                             __fmul_rn(pz, pz));
        float qp = __fadd_rn(__fadd_rn(__fmul_rn(qx, px), __fmul_rn(qy, py)),
                             __fmul_rn(qz, pz));
        float d2 = fmaxf(__fsub_rn(__fadd_rn(q2, p2), __fmul_rn(2.0f, qp)), 0.0f);
        out_idx[o] = (float)p;
        out_dist[o] = d2;
        ++o;
        mm &= mm - 1;
    }
}

// ================ fallback: R12 two-kernel path (verified 58.9us) ================
__global__ __launch_bounds__(256) void rs_cf(
    const float* __restrict__ pts, const float* __restrict__ qs,
    const float* __restrict__ rad, int* __restrict__ counts,
    unsigned long long* __restrict__ masks, int storeMasks,
    float* __restrict__ out_idx, float* __restrict__ out_dist,
    long long MN, int N, int M) {
    int t = threadIdx.x;
    int wv = t >> 6, lane = t & 63;
    int gw = blockIdx.x * 4 + wv;
    int nWaves = gridDim.x * 4;
    bool hasQ = (gw < M);
    int qc = hasQ ? gw : 0;
    float qx = qs[3 * qc], qy = qs[3 * qc + 1], qz = qs[3 * qc + 2];
    float q2 = __fadd_rn(__fadd_rn(__fmul_rn(qx, qx), __fmul_rn(qy, qy)),
                         __fmul_rn(qz, qz));
    float r = rad[qc];
    float r2 = hasQ ? __fmul_rn(r, r) : -1.0f;
    int nc = N >> 6;
    int vecIters = N >> 8;
    long long V = MN >> 2;
    long long perWave = (V + nWaves - 1) / nWaves;
    int fillIters = (int)((perWave + 63) >> 6);
    long long fbase = (long long)gw * perWave;
    long long fend = fbase + perWave;
    if (fend > V) fend = V;
    f32x4* vidx = (f32x4*)out_idx;
    f32x4* vdst = (f32x4*)out_dist;
    f32x4 vm1 = {-1.0f, -1.0f, -1.0f, -1.0f};
    f32x4 vz = {0.0f, 0.0f, 0.0f, 0.0f};
    int iters = vecIters > fillIters ? vecIters : fillIters;
    int cntLane = 0;
    int shift = (lane & 15) << 2;
    int wordSel = lane >> 4;
    for (int it = 0; it < iters; ++it) {
        if (it < fillIters) {
            long long fi = fbase + (long long)it * 64 + lane;
            if (fi < fend) { vidx[fi] = vm1; vdst[fi] = vz; }
        }
        if (it < vecIters) {
            const f32x4* pv = (const f32x4*)(pts + (size_t)it * 768);
            f32x4 v0 = pv[3 * lane + 0];
            f32x4 v1 = pv[3 * lane + 1];
            f32x4 v2 = pv[3 * lane + 2];
            float px[4] = {v0.x, v0.w, v1.z, v2.y};
            float py[4] = {v0.y, v1.x, v1.w, v2.z};
            float pz[4] = {v0.z, v1.y, v2.x, v2.w};
            unsigned nib = 0;
#pragma unroll
            for (int k = 0; k < 4; ++k) {
                float p2 = __fadd_rn(
                    __fadd_rn(__fmul_rn(px[k], px[k]), __fmul_rn(py[k], py[k])),
                    __fmul_rn(pz[k], pz[k]));
                float qp = __fadd_rn(
                    __fadd_rn(__fmul_rn(qx, px[k]), __fmul_rn(qy, py[k])),
                    __fmul_rn(qz, pz[k]));
                float d2 = __fsub_rn(__fadd_rn(q2, p2), __fmul_rn(2.0f, qp));
                bool pred = (d2 <= r2);
                nib |= (pred ? 1u : 0u) << k;
                cntLane += pred ? 1 : 0;
            }
            unsigned long long contrib = (unsigned long long)nib << shift;
#pragma unroll
            for (int s = 1; s < 16; s <<= 1) contrib |= __shfl_xor(contrib, s, 64);
            if (storeMasks && hasQ && (lane & 15) == 0)
                masks[(long long)gw * nc + (it << 2) + wordSel] = contrib;
        }
    }
    for (int c = vecIters << 2; c < nc; ++c) {
        int p = (c << 6) + lane;
        bool vld = (p < N);
        int pcl = vld ? p : 0;
        float px = pts[3 * pcl], py = pts[3 * pcl + 1], pz = pts[3 * pcl + 2];
        float p2 = __fadd_rn(__fadd_rn(__fmul_rn(px, px), __fmul_rn(py, py)),
                             __fmul_rn(pz, pz));
        float qp = __fadd_rn(__fadd_rn(__fmul_rn(qx, px), __fmul_rn(qy, py)),
                             __fmul_rn(qz, pz));
        float d2 = __fsub_rn(__fadd_rn(q2, p2), __fmul_rn(2.0f, qp));
        bool pred = vld && (d2 <= r2);
        unsigned long long b = __ballot(pred);
        if (storeMasks && hasQ && lane == 0) masks[(long long)gw * nc + c] = b;
        cntLane += pred ? 1 : 0;
    }
    for (int off = 32; off > 0; off >>= 1) cntLane += __shfl_down(cntLane, off, 64);
    if (hasQ && lane == 0) counts[gw] = cntLane;
}

__global__ __launch_bounds__(256) void rs_write(
    const float* __restrict__ pts, const float* __restrict__ qs,
    const float* __restrict__ rad,
    const int* __restrict__ counts, const unsigned long long* __restrict__ masks,
    int useMasks,
    float* __restrict__ out_idx, float* __restrict__ out_splits,
    float* __restrict__ out_dist, int N, int M) {
    __shared__ int s_scan[256];
    __shared__ int s_split[4097];
    int t = threadIdx.x;
    {
        int c[16];
        int sum = 0;
        int b16 = t * 16;
#pragma unroll
        for (int i = 0; i < 16; ++i) {
            int idx = b16 + i;
            int v = (idx < M) ? counts[idx] : 0;
            c[i] = sum;
            sum += v;
        }
        s_scan[t] = sum;
        __syncthreads();
        for (int off = 1; off < 256; off <<= 1) {
            int add = (t >= off) ? s_scan[t - off] : 0;
            __syncthreads();
            s_scan[t] += add;
            __syncthreads();
        }
        int excl = (t == 0) ? 0 : s_scan[t - 1];
#pragma unroll
        for (int i = 0; i < 16; ++i)
            if (b16 + i < M) s_split[b16 + i] = excl + c[i];
        if (t == 255) s_split[M] = excl + sum;
        __syncthreads();
    }
    if (blockIdx.x == 0) {
        for (int i = t; i <= M; i += 256) out_splits[i] = (float)s_split[i];
    }
    int wv = t >> 6, lane = t & 63;
    int w = blockIdx.x * 4 + wv;
    if (w >= M) return;
    float qxx = qs[3 * w], qyy = qs[3 * w + 1], qzz = qs[3 * w + 2];
    float q2 = __fadd_rn(__fadd_rn(__fmul_rn(qxx, qxx), __fmul_rn(qyy, qyy)),
                         __fmul_rn(qzz, qzz));
    long long base = s_split[w];
    int nc = N >> 6;
    if (useMasks) {
        const unsigned long long* mq = masks + (long long)w * nc;
        unsigned long long w0 = (lane < nc) ? mq[lane] : 0ull;
        unsigned long long w1 = (lane + 64 < nc) ? mq[lane + 64] : 0ull;
        int c0 = __popcll(w0), c1 = __popcll(w1);
        int i0 = c0, i1 = c1;
        for (int off = 1; off < 64; off <<= 1) {
            int t0 = __shfl_up(i0, off, 64);
            int t1 = __shfl_up(i1, off, 64);
            if (lane >= off) { i0 += t0; i1 += t1; }
        }
        int total0 = __shfl(i0, 63, 64);
        long long o = base + (i0 - c0);
        int pbase = lane << 6;
        unsigned long long mm = w0;
        while (mm) {
            int b = __ffsll((long long)mm) - 1;
            int p = pbase + b;
            float px = pts[3 * p], py = pts[3 * p + 1], pz = pts[3 * p + 2];
            float p2 = __fadd_rn(__fadd_rn(__fmul_rn(px, px), __fmul_rn(py, py)),
                                 __fmul_rn(pz, pz));
            float qp = __fadd_rn(__fadd_rn(__fmul_rn(qxx, px), __fmul_rn(qyy, py)),
                                 __fmul_rn(qzz, pz));
            float d2 = fmaxf(__fsub_rn(__fadd_rn(q2, p2), __fmul_rn(2.0f, qp)), 0.0f);
            out_idx[o] = (float)p;
            out_dist[o] = d2;
            ++o;
            mm &= mm - 1;
        }
        o = base + total0 + (i1 - c1);
        pbase = (lane + 64) << 6;
        mm = w1;
        while (mm) {
            int b = __ffsll((long long)mm) - 1;
            int p = pbase + b;
            float px = pts[3 * p], py = pts[3 * p + 1], pz = pts[3 * p + 2];
            float p2 = __fadd_rn(__fadd_rn(__fmul_rn(px, px), __fmul_rn(py, py)),
                                 __fmul_rn(pz, pz));
            float qp = __fadd_rn(__fadd_rn(__fmul_rn(qxx, px), __fmul_rn(qyy, py)),
                                 __fmul_rn(qzz, pz));
            float d2 = fmaxf(__fsub_rn(__fadd_rn(q2, p2), __fmul_rn(2.0f, qp)), 0.0f);
            out_idx[o] = (float)p;
            out_dist[o] = d2;
            ++o;
            mm &= mm - 1;
        }
    } else {
        float r = rad[w];
        float r2 = __fmul_rn(r, r);
        int cum = 0;
        unsigned long long lanemask = (1ull << lane) - 1ull;
        for (int p0 = 0; p0 < N; p0 += 64) {
            int p = p0 + lane;
            bool vld = (p < N);
            int pcl = vld ? p : 0;
            float px = pts[3 * pcl], py = pts[3 * pcl + 1], pz = pts[3 * pcl + 2];
            float p2 = __fadd_rn(__fadd_rn(__fmul_rn(px, px), __fmul_rn(py, py)),
                                 __fmul_rn(pz, pz));
            float qp = __fadd_rn(__fadd_rn(__fmul_rn(qxx, px), __fmul_rn(qyy, py)),
                                 __fmul_rn(qzz, pz));
            float d2 = __fsub_rn(__fadd_rn(q2, p2), __fmul_rn(2.0f, qp));
            bool pred = vld && (d2 <= r2);
            unsigned long long mask = __ballot(pred);
            if (pred) {
                long long pos = base + cum + __popcll(mask & lanemask);
                out_idx[pos] = (float)p;
                out_dist[pos] = fmaxf(d2, 0.0f);
            }
            cum += __popcll(mask);
        }
    }
}

extern "C" void kernel_launch(void* const* d_in, const int* in_sizes, int n_in,
                              void* d_out, int out_size, void* d_ws, size_t ws_size,
                              hipStream_t stream) {
    const float* points = (const float*)d_in[0];
    const float* queries = (const float*)d_in[1];
    const float* radii = (const float*)d_in[2];
    int N = in_sizes[0] / 3;
    int M = in_sizes[1] / 3;
    long long MN = (long long)M * (long long)N;

    float* out = (float*)d_out;
    float* out_idx = out;
    float* out_splits = out + MN;
    float* out_dist = out + MN + M + 1;

    // running-offset ws allocator (R2 lesson: never hand-sum offsets)
    char* ws = (char*)d_ws;
    size_t off = 0;
    auto take = [&](size_t bytes) -> size_t {
        size_t o = off;
        off += (bytes + 255) & ~(size_t)255;
        return o;
    };
    size_t o_counts = take((size_t)M * 4);
    size_t o_splits = take((size_t)(M + 1) * 4);
    size_t o_flags = take(8);
    size_t o_masks = take((size_t)M * (size_t)(N / 64) * 8);
    bool useMasks = (off <= ws_size) && ((N >> 6) <= 128);
    int* counts = (int*)(ws + o_counts);
    int* splits_i = (int*)(ws + o_splits);
    int* flags = (int*)(ws + o_flags);
    unsigned long long* masks = (unsigned long long*)(ws + o_masks);

    int C = (M + 3) / 4;  // 4 waves/block, 1 query/wave
    // fused path requires: masks fit, scan supports M<=4096, all C blocks
    // co-resident (C <= 1024 with launch_bounds(256,4) -> >=4 blocks/CU x 256 CUs)
    bool fusedOK = useMasks && (M <= 4096) && (C <= 1024) && (N % 64 == 0);
    if (fusedOK) {
        rs_zero<<<1, 64, 0, stream>>>(flags);
        rs_all<<<C, 256, 0, stream>>>(points, queries, radii, counts, masks, out_idx,
                                      out_dist, out_splits, splits_i, flags, MN, N, M);
    } else {
        rs_cf<<<C, 256, 0, stream>>>(points, queries, radii, counts, masks,
                                     useMasks ? 1 : 0, out_idx, out_dist, MN, N, M);
        rs_write<<<C, 256, 0, stream>>>(points, queries, radii, counts, masks,
                                        useMasks ? 1 : 0, out_idx, out_splits,
                                        out_dist, N, M);
    }
}

// Round 16
// 76.702 us; speedup vs baseline: 3.1695x; 3.1695x over previous
//
#include <hip/hip_runtime.h>

// Radius search (L2^2), single segment, M=4096 queries x N=8192 points.
// Out (float32, concat): [0,MN) packed idx (pad -1) | [MN,MN+M+1) row splits |
//                        [MN+M+1, 2MN+M+1) packed d2 (pad 0).
// Exact numpy fp32 op order (NO fma):
//   q2=(qx*qx+qy*qy)+qz*qz ; p2=(px*px+py*py)+pz*pz ; qp=(qx*px+qy*py)+qz*pz
//   d2=max((q2+p2)-2*qp, 0) ; mask: d2<=r*r  (max irrelevant for mask, r2>0)
//
// HARD LESSONS: no hipMemsetAsync in-graph (R9/R14: +20..155us); no device
// spin barrier (R15: cross-XCD atomic storm, 1.1TB/s); no coop launch (R7);
// no serial-kernel fill splits (R11/R13). R12 = 58.9us champion.
// R16 = R12 with K1 wave-specialized: parity-interleaved {count blocks
// (R12's vectorized count, no fills)} | {pure-fill blocks (tight aligned
// store loop)}. Mechanism: count VALU/shfl no longer steals store-issue
// slots, and dist stores get head-aligned (out_dist is 4B-misaligned for
// 16B stores). K2 = R12's verified scan+pack, untouched.

typedef float f32x4 __attribute__((ext_vector_type(4)));

__device__ __forceinline__ void fill_region(float* __restrict__ base, long long n,
                                            float val, long long tid, long long nth) {
    long long head = (long long)(((16u - ((unsigned)(size_t)base & 15u)) & 15u) >> 2);
    if (head > n) head = n;
    for (long long i = tid; i < head; i += nth) base[i] = val;
    long long nv = (n - head) >> 2;
    f32x4* v = (f32x4*)(base + head);
    f32x4 vv = {val, val, val, val};
    for (long long i = tid; i < nv; i += nth) v[i] = vv;
    for (long long i = head + (nv << 2) + tid; i < n; i += nth) base[i] = val;
}

// ---------------- K1: parity-specialized count | fill ----------------
__global__ __launch_bounds__(256) void rs_main(
    const float* __restrict__ pts, const float* __restrict__ qs,
    const float* __restrict__ rad, int* __restrict__ counts,
    unsigned long long* __restrict__ masks, int storeMasks,
    float* __restrict__ out_idx, float* __restrict__ out_dist,
    long long MN, int N, int M, int CB, int FB) {
    int bid = blockIdx.x;
    int t = threadIdx.x;

    int cid = -1, fid = -1;
    if (CB == FB) {  // parity interleave (harness shape)
        if ((bid & 1) == 0) cid = bid >> 1;
        else fid = bid >> 1;
    } else {
        if (bid < CB) cid = bid;
        else fid = bid - CB;
    }

    if (fid >= 0) {
        // ---- pure fill block: tight aligned store loops, both regions ----
        long long tid = (long long)fid * 256 + t;
        long long nth = (long long)FB * 256;
        fill_region(out_idx, MN, -1.0f, tid, nth);
        fill_region(out_dist, MN, 0.0f, tid, nth);
        return;
    }

    // ---- count block: 4 waves, 1 query/wave (R12's count, fills removed) ----
    int wv = t >> 6, lane = t & 63;
    int gw = cid * 4 + wv;
    if (gw >= M) return;
    float qx = qs[3 * gw], qy = qs[3 * gw + 1], qz = qs[3 * gw + 2];
    float q2 = __fadd_rn(__fadd_rn(__fmul_rn(qx, qx), __fmul_rn(qy, qy)),
                         __fmul_rn(qz, qz));
    float r = rad[gw];
    float r2 = __fmul_rn(r, r);

    int nc = N >> 6;           // 64-pt mask words
    int vecIters = N >> 8;     // 256 pts/iter (4 consecutive/lane)
    int cntLane = 0;
    int shift = (lane & 15) << 2;
    int wordSel = lane >> 4;

    for (int it = 0; it < vecIters; ++it) {
        const f32x4* pv = (const f32x4*)(pts + (size_t)it * 768);
        f32x4 v0 = pv[3 * lane + 0];
        f32x4 v1 = pv[3 * lane + 1];
        f32x4 v2 = pv[3 * lane + 2];
        float px[4] = {v0.x, v0.w, v1.z, v2.y};
        float py[4] = {v0.y, v1.x, v1.w, v2.z};
        float pz[4] = {v0.z, v1.y, v2.x, v2.w};
        unsigned nib = 0;
#pragma unroll
        for (int k = 0; k < 4; ++k) {
            float p2 = __fadd_rn(
                __fadd_rn(__fmul_rn(px[k], px[k]), __fmul_rn(py[k], py[k])),
                __fmul_rn(pz[k], pz[k]));
            float qp = __fadd_rn(
                __fadd_rn(__fmul_rn(qx, px[k]), __fmul_rn(qy, py[k])),
                __fmul_rn(qz, pz[k]));
            float d2 = __fsub_rn(__fadd_rn(q2, p2), __fmul_rn(2.0f, qp));
            bool pred = (d2 <= r2);
            nib |= (pred ? 1u : 0u) << k;
            cntLane += pred ? 1 : 0;
        }
        unsigned long long contrib = (unsigned long long)nib << shift;
#pragma unroll
        for (int s = 1; s < 16; s <<= 1) contrib |= __shfl_xor(contrib, s, 64);
        if (storeMasks && (lane & 15) == 0)
            masks[(long long)gw * nc + (it << 2) + wordSel] = contrib;
    }
    // tail (N % 256 != 0): strided scalar + ballot path
    for (int c = vecIters << 2; c < nc; ++c) {
        int p = (c << 6) + lane;
        bool vld = (p < N);
        int pcl = vld ? p : 0;
        float px = pts[3 * pcl], py = pts[3 * pcl + 1], pz = pts[3 * pcl + 2];
        float p2 = __fadd_rn(__fadd_rn(__fmul_rn(px, px), __fmul_rn(py, py)),
                             __fmul_rn(pz, pz));
        float qp = __fadd_rn(__fadd_rn(__fmul_rn(qx, px), __fmul_rn(qy, py)),
                             __fmul_rn(qz, pz));
        float d2 = __fsub_rn(__fadd_rn(q2, p2), __fmul_rn(2.0f, qp));
        bool pred = vld && (d2 <= r2);
        unsigned long long b = __ballot(pred);
        if (storeMasks && lane == 0) masks[(long long)gw * nc + c] = b;
        cntLane += pred ? 1 : 0;
    }
    for (int off = 32; off > 0; off >>= 1) cntLane += __shfl_down(cntLane, off, 64);
    if (lane == 0) counts[gw] = cntLane;
}

// ---------------- K2: redundant cheap scan + mask pack (R12 verified) ----------------
__global__ __launch_bounds__(256) void rs_write(
    const float* __restrict__ pts, const float* __restrict__ qs,
    const float* __restrict__ rad,
    const int* __restrict__ counts, const unsigned long long* __restrict__ masks,
    int useMasks,
    float* __restrict__ out_idx, float* __restrict__ out_splits,
    float* __restrict__ out_dist, int N, int M) {
    __shared__ int s_scan[256];
    __shared__ int s_split[4097];  // M <= 4096
    int t = threadIdx.x;

    {
        int c[16];
        int sum = 0;
        int b16 = t * 16;
#pragma unroll
        for (int i = 0; i < 16; ++i) {
            int idx = b16 + i;
            int v = (idx < M) ? counts[idx] : 0;
            c[i] = sum;
            sum += v;
        }
        s_scan[t] = sum;
        __syncthreads();
        for (int off = 1; off < 256; off <<= 1) {
            int add = (t >= off) ? s_scan[t - off] : 0;
            __syncthreads();
            s_scan[t] += add;
            __syncthreads();
        }
        int excl = (t == 0) ? 0 : s_scan[t - 1];
#pragma unroll
        for (int i = 0; i < 16; ++i)
            if (b16 + i < M) s_split[b16 + i] = excl + c[i];
        if (t == 255) s_split[M] = excl + sum;
        __syncthreads();
    }

    if (blockIdx.x == 0) {
        for (int i = t; i <= M; i += 256) out_splits[i] = (float)s_split[i];
    }

    int wv = t >> 6, lane = t & 63;
    int w = blockIdx.x * 4 + wv;  // one wave per query
    if (w >= M) return;
    float qxx = qs[3 * w], qyy = qs[3 * w + 1], qzz = qs[3 * w + 2];
    float q2 = __fadd_rn(__fadd_rn(__fmul_rn(qxx, qxx), __fmul_rn(qyy, qyy)),
                         __fmul_rn(qzz, qzz));
    long long base = s_split[w];
    int nc = N >> 6;

    if (useMasks) {
        const unsigned long long* mq = masks + (long long)w * nc;
        unsigned long long w0 = (lane < nc) ? mq[lane] : 0ull;
        unsigned long long w1 = (lane + 64 < nc) ? mq[lane + 64] : 0ull;
        int c0 = __popcll(w0), c1 = __popcll(w1);
        int i0 = c0, i1 = c1;
        for (int off = 1; off < 64; off <<= 1) {
            int t0 = __shfl_up(i0, off, 64);
            int t1 = __shfl_up(i1, off, 64);
            if (lane >= off) { i0 += t0; i1 += t1; }
        }
        int total0 = __shfl(i0, 63, 64);

        long long o = base + (i0 - c0);
        int pbase = lane << 6;
        unsigned long long mm = w0;
        while (mm) {
            int b = __ffsll((long long)mm) - 1;
            int p = pbase + b;
            float px = pts[3 * p], py = pts[3 * p + 1], pz = pts[3 * p + 2];
            float p2 = __fadd_rn(__fadd_rn(__fmul_rn(px, px), __fmul_rn(py, py)),
                                 __fmul_rn(pz, pz));
            float qp = __fadd_rn(__fadd_rn(__fmul_rn(qxx, px), __fmul_rn(qyy, py)),
                                 __fmul_rn(qzz, pz));
            float d2 = fmaxf(__fsub_rn(__fadd_rn(q2, p2), __fmul_rn(2.0f, qp)), 0.0f);
            out_idx[o] = (float)p;
            out_dist[o] = d2;
            ++o;
            mm &= mm - 1;
        }
        o = base + total0 + (i1 - c1);
        pbase = (lane + 64) << 6;
        mm = w1;
        while (mm) {
            int b = __ffsll((long long)mm) - 1;
            int p = pbase + b;
            float px = pts[3 * p], py = pts[3 * p + 1], pz = pts[3 * p + 2];
            float p2 = __fadd_rn(__fadd_rn(__fmul_rn(px, px), __fmul_rn(py, py)),
                                 __fmul_rn(pz, pz));
            float qp = __fadd_rn(__fadd_rn(__fmul_rn(qxx, px), __fmul_rn(qyy, py)),
                                 __fmul_rn(qzz, pz));
            float d2 = fmaxf(__fsub_rn(__fadd_rn(q2, p2), __fmul_rn(2.0f, qp)), 0.0f);
            out_idx[o] = (float)p;
            out_dist[o] = d2;
            ++o;
            mm &= mm - 1;
        }
    } else {
        // fallback: recompute + ballot pack (only if masks don't fit in ws)
        float r = rad[w];
        float r2 = __fmul_rn(r, r);
        int cum = 0;
        unsigned long long lanemask = (1ull << lane) - 1ull;
        for (int p0 = 0; p0 < N; p0 += 64) {
            int p = p0 + lane;
            bool vld = (p < N);
            int pcl = vld ? p : 0;
            float px = pts[3 * pcl], py = pts[3 * pcl + 1], pz = pts[3 * pcl + 2];
            float p2 = __fadd_rn(__fadd_rn(__fmul_rn(px, px), __fmul_rn(py, py)),
                                 __fmul_rn(pz, pz));
            float qp = __fadd_rn(__fadd_rn(__fmul_rn(qxx, px), __fmul_rn(qyy, py)),
                                 __fmul_rn(qzz, pz));
            float d2 = __fsub_rn(__fadd_rn(q2, p2), __fmul_rn(2.0f, qp));
            bool pred = vld && (d2 <= r2);
            unsigned long long mask = __ballot(pred);
            if (pred) {
                long long pos = base + cum + __popcll(mask & lanemask);
                out_idx[pos] = (float)p;
                out_dist[pos] = fmaxf(d2, 0.0f);
            }
            cum += __popcll(mask);
        }
    }
}

extern "C" void kernel_launch(void* const* d_in, const int* in_sizes, int n_in,
                              void* d_out, int out_size, void* d_ws, size_t ws_size,
                              hipStream_t stream) {
    const float* points = (const float*)d_in[0];
    const float* queries = (const float*)d_in[1];
    const float* radii = (const float*)d_in[2];
    int N = in_sizes[0] / 3;
    int M = in_sizes[1] / 3;
    long long MN = (long long)M * (long long)N;

    float* out = (float*)d_out;
    float* out_idx = out;
    float* out_splits = out + MN;
    float* out_dist = out + MN + M + 1;

    // running-offset ws allocator (R2 lesson: never hand-sum offsets)
    char* ws = (char*)d_ws;
    size_t off = 0;
    auto take = [&](size_t bytes) -> size_t {
        size_t o = off;
        off += (bytes + 255) & ~(size_t)255;
        return o;
    };
    size_t o_counts = take((size_t)M * 4);
    size_t o_masks = take((size_t)M * (size_t)(N / 64) * 8);
    bool useMasks = (off <= ws_size) && ((N >> 6) <= 128);  // pack path needs nc<=128
    int* counts = (int*)(ws + o_counts);
    unsigned long long* masks = (unsigned long long*)(ws + o_masks);

    int CB = (M + 3) / 4;  // count blocks: 4 waves/block, 1 query/wave
    int FB = CB;           // equal fill blocks -> parity interleave
    rs_main<<<CB + FB, 256, 0, stream>>>(points, queries, radii, counts, masks,
                                         useMasks ? 1 : 0, out_idx, out_dist, MN, N, M,
                                         CB, FB);
    int writeBlocks = (M + 3) / 4;  // 4 queries (waves) per 256-thr block
    rs_write<<<writeBlocks, 256, 0, stream>>>(points, queries, radii, counts, masks,
                                              useMasks ? 1 : 0, out_idx, out_splits,
                                              out_dist, N, M);
}

// Round 17
// 58.708 us; speedup vs baseline: 4.1409x; 1.3065x over previous
//
#include <hip/hip_runtime.h>

// Radius search (L2^2), single segment, M=4096 queries x N=8192 points.
// Out (float32, concat): [0,MN) packed idx (pad -1) | [MN,MN+M+1) row splits |
//                        [MN+M+1, 2MN+M+1) packed d2 (pad 0).
// Exact numpy fp32 op order (NO fma):
//   q2=(qx*qx+qy*qy)+qz*qz ; p2=(px*px+py*py)+pz*pz ; qp=(qx*px+qy*py)+qz*pz
//   d2=max((q2+p2)-2*qp, 0) ; mask: d2<=r*r  (max irrelevant for mask, r2>0)
//
// HARD LESSONS: no in-graph memset (R9/R14); no device spin barrier (R15);
// no coop launch (R7); no serial fill splits (R11/R13); no block-role
// specialization (R8/R13/R16 all lose to instruction-woven fill).
// R17 = R12 (58.9us champion) + ONE fix: out_dist is 4B-misaligned mod 16,
// so R12's f32x4 dist stores were split transactions (~half rate; explains
// K1's 5.9 vs 6.9 TB/s). Dist fill now runs over the aligned interior
// out_dist+3 (head/tail scalars by wave 0).

typedef float f32x4 __attribute__((ext_vector_type(4)));

// ---------------- K1: fused count (3xfloat4 loads) + woven ALIGNED pad-fill ----------------
__global__ __launch_bounds__(256) void rs_fused(
    const float* __restrict__ pts, const float* __restrict__ qs,
    const float* __restrict__ rad, int* __restrict__ counts,
    unsigned long long* __restrict__ masks, int storeMasks,
    float* __restrict__ out_idx, float* __restrict__ out_dist,
    long long MN, int N, int M) {
    int t = threadIdx.x;
    int wv = t >> 6, lane = t & 63;
    int gw = blockIdx.x * 4 + wv;       // wave id == query id
    int nWaves = gridDim.x * 4;

    bool hasQ = (gw < M);
    int qc = hasQ ? gw : 0;
    float qx = qs[3 * qc], qy = qs[3 * qc + 1], qz = qs[3 * qc + 2];
    float q2 = __fadd_rn(__fadd_rn(__fmul_rn(qx, qx), __fmul_rn(qy, qy)),
                         __fmul_rn(qz, qz));
    float r = rad[qc];
    float r2 = hasQ ? __fmul_rn(r, r) : -1.0f;  // raw d2 > -1 always

    int nc = N >> 6;                      // 64-pt mask words
    int vecIters = N >> 8;                // 256 pts/iter (4 consecutive/lane)

    // idx region: out_idx is 16B-aligned (d_out base), MN % 4 == 0
    long long nvI = MN >> 2;
    // dist region: align to 16B interior
    int headD = (int)(((16u - ((unsigned)(size_t)out_dist & 15u)) & 15u) >> 2);
    if ((long long)headD > MN) headD = (int)MN;
    long long nvD = (MN - headD) >> 2;
    int tailD = (int)(MN - headD - (nvD << 2));
    f32x4* vidx = (f32x4*)out_idx;
    f32x4* vdst = (f32x4*)(out_dist + headD);
    f32x4 vm1 = {-1.0f, -1.0f, -1.0f, -1.0f};
    f32x4 vz = {0.0f, 0.0f, 0.0f, 0.0f};

    long long maxV = nvI > nvD ? nvI : nvD;
    long long perWave = (maxV + nWaves - 1) / nWaves;
    int fillIters = (int)((perWave + 63) >> 6);
    long long fbase = (long long)gw * perWave;
    long long fendI = fbase + perWave; if (fendI > nvI) fendI = nvI;
    long long fendD = fbase + perWave; if (fendD > nvD) fendD = nvD;

    // head/tail scalars of dist region: wave 0 (once)
    if (gw == 0) {
        if (lane < headD) out_dist[lane] = 0.0f;
        if (lane < tailD) out_dist[headD + (nvD << 2) + lane] = 0.0f;
    }

    int iters = vecIters > fillIters ? vecIters : fillIters;
    int cntLane = 0;
    int shift = (lane & 15) << 2;
    int wordSel = lane >> 4;  // which of the 4 mask words this lane's group owns

    for (int it = 0; it < iters; ++it) {
        // ---- fill step: fire-and-forget coalesced ALIGNED stores ----
        if (it < fillIters) {
            long long fi = fbase + (long long)it * 64 + lane;
            if (fi < fendI) vidx[fi] = vm1;
            if (fi < fendD) vdst[fi] = vz;
        }
        // ---- count step: 4 consecutive points/lane via 3x float4 ----
        if (it < vecIters) {
            const f32x4* pv = (const f32x4*)(pts + (size_t)it * 768);
            f32x4 v0 = pv[3 * lane + 0];
            f32x4 v1 = pv[3 * lane + 1];
            f32x4 v2 = pv[3 * lane + 2];
            float px[4] = {v0.x, v0.w, v1.z, v2.y};
            float py[4] = {v0.y, v1.x, v1.w, v2.z};
            float pz[4] = {v0.z, v1.y, v2.x, v2.w};
            unsigned nib = 0;
#pragma unroll
            for (int k = 0; k < 4; ++k) {
                float p2 = __fadd_rn(
                    __fadd_rn(__fmul_rn(px[k], px[k]), __fmul_rn(py[k], py[k])),
                    __fmul_rn(pz[k], pz[k]));
                float qp = __fadd_rn(
                    __fadd_rn(__fmul_rn(qx, px[k]), __fmul_rn(qy, py[k])),
                    __fmul_rn(qz, pz[k]));
                float d2 = __fsub_rn(__fadd_rn(q2, p2), __fmul_rn(2.0f, qp));
                bool pred = (d2 <= r2);
                nib |= (pred ? 1u : 0u) << k;
                cntLane += pred ? 1 : 0;
            }
            // build the 4 mask words: OR-reduce nibble<<shift in 16-lane groups
            unsigned long long contrib = (unsigned long long)nib << shift;
#pragma unroll
            for (int s = 1; s < 16; s <<= 1) contrib |= __shfl_xor(contrib, s, 64);
            if (storeMasks && hasQ && (lane & 15) == 0)
                masks[(long long)gw * nc + (it << 2) + wordSel] = contrib;
        }
    }
    // ---- tail (N % 256 != 0): strided scalar + ballot path ----
    for (int c = vecIters << 2; c < nc; ++c) {
        int p = (c << 6) + lane;
        bool vld = (p < N);
        int pcl = vld ? p : 0;
        float px = pts[3 * pcl], py = pts[3 * pcl + 1], pz = pts[3 * pcl + 2];
        float p2 = __fadd_rn(__fadd_rn(__fmul_rn(px, px), __fmul_rn(py, py)),
                             __fmul_rn(pz, pz));
        float qp = __fadd_rn(__fadd_rn(__fmul_rn(qx, px), __fmul_rn(qy, py)),
                             __fmul_rn(qz, pz));
        float d2 = __fsub_rn(__fadd_rn(q2, p2), __fmul_rn(2.0f, qp));
        bool pred = vld && (d2 <= r2);
        unsigned long long b = __ballot(pred);
        if (storeMasks && hasQ && lane == 0) masks[(long long)gw * nc + c] = b;
        cntLane += pred ? 1 : 0;
    }
    // wave-reduce the per-lane counts
    for (int off = 32; off > 0; off >>= 1) cntLane += __shfl_down(cntLane, off, 64);
    if (hasQ && lane == 0) counts[gw] = cntLane;
}

// ---------------- K2: redundant cheap scan + mask pack (R12 verified) ----------------
__global__ __launch_bounds__(256) void rs_write(
    const float* __restrict__ pts, const float* __restrict__ qs,
    const float* __restrict__ rad,
    const int* __restrict__ counts, const unsigned long long* __restrict__ masks,
    int useMasks,
    float* __restrict__ out_idx, float* __restrict__ out_splits,
    float* __restrict__ out_dist, int N, int M) {
    __shared__ int s_scan[256];
    __shared__ int s_split[4097];  // M <= 4096
    int t = threadIdx.x;

    // per-block exclusive scan of counts[M]: 16 per thread + 256 ladder
    {
        int c[16];
        int sum = 0;
        int b16 = t * 16;
#pragma unroll
        for (int i = 0; i < 16; ++i) {
            int idx = b16 + i;
            int v = (idx < M) ? counts[idx] : 0;
            c[i] = sum;
            sum += v;
        }
        s_scan[t] = sum;
        __syncthreads();
        for (int off = 1; off < 256; off <<= 1) {
            int add = (t >= off) ? s_scan[t - off] : 0;
            __syncthreads();
            s_scan[t] += add;
            __syncthreads();
        }
        int excl = (t == 0) ? 0 : s_scan[t - 1];
#pragma unroll
        for (int i = 0; i < 16; ++i)
            if (b16 + i < M) s_split[b16 + i] = excl + c[i];
        if (t == 255) s_split[M] = excl + sum;
        __syncthreads();
    }

    if (blockIdx.x == 0) {
        for (int i = t; i <= M; i += 256) out_splits[i] = (float)s_split[i];
    }

    int wv = t >> 6, lane = t & 63;
    int w = blockIdx.x * 4 + wv;  // one wave per query
    if (w >= M) return;
    float qxx = qs[3 * w], qyy = qs[3 * w + 1], qzz = qs[3 * w + 2];
    float q2 = __fadd_rn(__fadd_rn(__fmul_rn(qxx, qxx), __fmul_rn(qyy, qyy)),
                         __fmul_rn(qzz, qzz));
    long long base = s_split[w];
    int nc = N >> 6;

    if (useMasks) {
        const unsigned long long* mq = masks + (long long)w * nc;
        unsigned long long w0 = (lane < nc) ? mq[lane] : 0ull;
        unsigned long long w1 = (lane + 64 < nc) ? mq[lane + 64] : 0ull;
        int c0 = __popcll(w0), c1 = __popcll(w1);
        int i0 = c0, i1 = c1;
        for (int off = 1; off < 64; off <<= 1) {
            int t0 = __shfl_up(i0, off, 64);
            int t1 = __shfl_up(i1, off, 64);
            if (lane >= off) { i0 += t0; i1 += t1; }
        }
        int total0 = __shfl(i0, 63, 64);

        long long o = base + (i0 - c0);
        int pbase = lane << 6;
        unsigned long long mm = w0;
        while (mm) {
            int b = __ffsll((long long)mm) - 1;
            int p = pbase + b;
            float px = pts[3 * p], py = pts[3 * p + 1], pz = pts[3 * p + 2];
            float p2 = __fadd_rn(__fadd_rn(__fmul_rn(px, px), __fmul_rn(py, py)),
                                 __fmul_rn(pz, pz));
            float qp = __fadd_rn(__fadd_rn(__fmul_rn(qxx, px), __fmul_rn(qyy, py)),
                                 __fmul_rn(qzz, pz));
            float d2 = fmaxf(__fsub_rn(__fadd_rn(q2, p2), __fmul_rn(2.0f, qp)), 0.0f);
            out_idx[o] = (float)p;
            out_dist[o] = d2;
            ++o;
            mm &= mm - 1;
        }
        o = base + total0 + (i1 - c1);
        pbase = (lane + 64) << 6;
        mm = w1;
        while (mm) {
            int b = __ffsll((long long)mm) - 1;
            int p = pbase + b;
            float px = pts[3 * p], py = pts[3 * p + 1], pz = pts[3 * p + 2];
            float p2 = __fadd_rn(__fadd_rn(__fmul_rn(px, px), __fmul_rn(py, py)),
                                 __fmul_rn(pz, pz));
            float qp = __fadd_rn(__fadd_rn(__fmul_rn(qxx, px), __fmul_rn(qyy, py)),
                                 __fmul_rn(qzz, pz));
            float d2 = fmaxf(__fsub_rn(__fadd_rn(q2, p2), __fmul_rn(2.0f, qp)), 0.0f);
            out_idx[o] = (float)p;
            out_dist[o] = d2;
            ++o;
            mm &= mm - 1;
        }
    } else {
        // fallback: recompute + ballot pack (only if masks don't fit in ws)
        float r = rad[w];
        float r2 = __fmul_rn(r, r);
        int cum = 0;
        unsigned long long lanemask = (1ull << lane) - 1ull;
        for (int p0 = 0; p0 < N; p0 += 64) {
            int p = p0 + lane;
            bool vld = (p < N);
            int pcl = vld ? p : 0;
            float px = pts[3 * pcl], py = pts[3 * pcl + 1], pz = pts[3 * pcl + 2];
            float p2 = __fadd_rn(__fadd_rn(__fmul_rn(px, px), __fmul_rn(py, py)),
                                 __fmul_rn(pz, pz));
            float qp = __fadd_rn(__fadd_rn(__fmul_rn(qxx, px), __fmul_rn(qyy, py)),
                                 __fmul_rn(qzz, pz));
            float d2 = __fsub_rn(__fadd_rn(q2, p2), __fmul_rn(2.0f, qp));
            bool pred = vld && (d2 <= r2);
            unsigned long long mask = __ballot(pred);
            if (pred) {
                long long pos = base + cum + __popcll(mask & lanemask);
                out_idx[pos] = (float)p;
                out_dist[pos] = fmaxf(d2, 0.0f);
            }
            cum += __popcll(mask);
        }
    }
}

extern "C" void kernel_launch(void* const* d_in, const int* in_sizes, int n_in,
                              void* d_out, int out_size, void* d_ws, size_t ws_size,
                              hipStream_t stream) {
    const float* points = (const float*)d_in[0];
    const float* queries = (const float*)d_in[1];
    const float* radii = (const float*)d_in[2];
    int N = in_sizes[0] / 3;
    int M = in_sizes[1] / 3;
    long long MN = (long long)M * (long long)N;

    float* out = (float*)d_out;
    float* out_idx = out;
    float* out_splits = out + MN;
    float* out_dist = out + MN + M + 1;

    // running-offset ws allocator (R2 lesson: never hand-sum offsets)
    char* ws = (char*)d_ws;
    size_t off = 0;
    auto take = [&](size_t bytes) -> size_t {
        size_t o = off;
        off += (bytes + 255) & ~(size_t)255;
        return o;
    };
    size_t o_counts = take((size_t)M * 4);
    size_t o_masks = take((size_t)M * (size_t)(N / 64) * 8);
    bool useMasks = (off <= ws_size) && ((N >> 6) <= 128);  // pack path needs nc<=128
    int* counts = (int*)(ws + o_counts);
    unsigned long long* masks = (unsigned long long*)(ws + o_masks);

    int C = (M + 3) / 4;  // 4 waves/block, 1 query/wave; waves also fill
    rs_fused<<<C, 256, 0, stream>>>(points, queries, radii, counts, masks,
                                    useMasks ? 1 : 0, out_idx, out_dist, MN, N, M);
    int writeBlocks = (M + 3) / 4;  // 4 queries (waves) per 256-thr block
    rs_write<<<writeBlocks, 256, 0, stream>>>(points, queries, radii, counts, masks,
                                              useMasks ? 1 : 0, out_idx, out_splits,
                                              out_dist, N, M);
}